// Round 5
// baseline (156.779 us; speedup 1.0000x reference)
//
#include <hip/hip_runtime.h>
#include <hip/hip_bf16.h>

// DeepPM Transformer encoder layer (round 4): bf16 MFMA everywhere;
// padded-M-tile skip in all GEMMs (rows >= lens[b] are dead work: every op is
// row-local except attention, which already bounds itself to valid rows).
// attention: static-max softmax + setprio around MFMA clusters.
// B=8, L=1024, D=256, H=8 (DH=32), DFF=2048.

#define BB   8
#define LL   1024
#define DD   256
#define HHN  8
#define DHH  32
#define DFFN 2048

typedef __attribute__((ext_vector_type(8))) __bf16 bf16x8;
typedef __attribute__((ext_vector_type(4))) float f32x4;

__device__ inline void gload16(const void* g, void* l) {
  __builtin_amdgcn_global_load_lds(
      (const __attribute__((address_space(1))) void*)g,
      (__attribute__((address_space(3))) void*)l, 16, 0, 0);
}

// ---------------------------------------------------------------------------
__global__ void compute_lens_kernel(const unsigned char* __restrict__ mb,
                                    int* __restrict__ lens) {
  __shared__ int flag3f, flagNA;
  __shared__ int cnt[BB];
  const int tid = threadIdx.x;
  if (tid == 0) { flag3f = 0; flagNA = 0; }
  if (tid < BB) cnt[tid] = 0;
  __syncthreads();
  for (int i = tid; i < BB * LL; i += blockDim.x) {
    unsigned char v = mb[i];
    if (v) {
      if ((i & 3) == 3 && v == 0x3F) flag3f = 1;
      else if (i & 3) flagNA = 1;
    }
  }
  __syncthreads();
  const bool isfloat = (flag3f != 0);
  const bool isbool  = (!isfloat) && (flagNA != 0);
  if (isbool) {
    for (int i = tid; i < BB * LL; i += blockDim.x)
      if (mb[i] == 0) atomicAdd(&cnt[i >> 10], 1);
  } else {
    const int* mi = (const int*)mb;
    for (int i = tid; i < BB * LL; i += blockDim.x)
      if (mi[i] == 0) atomicAdd(&cnt[i >> 10], 1);
  }
  __syncthreads();
  if (tid < BB) lens[tid] = cnt[tid];
}

// ---------------------------------------------------------------------------
// Fused fp32->bf16 conversion of 4 arrays (all sizes divisible by 8).
// ---------------------------------------------------------------------------
__global__ __launch_bounds__(256) void cvt4_kernel(
    const float* __restrict__ s0, __hip_bfloat16* __restrict__ d0, int n0,
    const float* __restrict__ s1, __hip_bfloat16* __restrict__ d1, int n1,
    const float* __restrict__ s2, __hip_bfloat16* __restrict__ d2, int n2,
    const float* __restrict__ s3, __hip_bfloat16* __restrict__ d3, int n3) {
  int i = (blockIdx.x * 256 + threadIdx.x) * 8;
  const float* s;
  __hip_bfloat16* d;
  if (i < n0) { s = s0; d = d0; }
  else if (i < n0 + n1) { s = s1; d = d1; i -= n0; }
  else if (i < n0 + n1 + n2) { s = s2; d = d2; i -= n0 + n1; }
  else if (i < n0 + n1 + n2 + n3) { s = s3; d = d3; i -= n0 + n1 + n2; }
  else return;
  const float4 a = *(const float4*)(s + i);
  const float4 b = *(const float4*)(s + i + 4);
  bf16x8 o;
  o[0] = (__bf16)a.x; o[1] = (__bf16)a.y; o[2] = (__bf16)a.z; o[3] = (__bf16)a.w;
  o[4] = (__bf16)b.x; o[5] = (__bf16)b.y; o[6] = (__bf16)b.z; o[7] = (__bf16)b.w;
  *(bf16x8*)(d + i) = o;
}

// ---------------------------------------------------------------------------
// Wc = proj_w @ out_w (bf16); bc = proj_b + proj_w @ out_b.
// 64 blocks x 4 rows: out_w read coalesced once per block-pass, proj_w as
// wave-uniform scalar loads (s_load), 4 fma per loaded out_w element.
// ---------------------------------------------------------------------------
__global__ __launch_bounds__(256) void wc_kernel(
    const float* __restrict__ proj_w, const float* __restrict__ out_w,
    const float* __restrict__ proj_b, const float* __restrict__ out_b,
    __hip_bfloat16* __restrict__ Wc, float* __restrict__ bc) {
  const int i0 = blockIdx.x << 2;
  const int k = threadIdx.x;
  float acc[4] = {0.f, 0.f, 0.f, 0.f};
  for (int n = 0; n < DD; ++n) {
    const float won = out_w[n * DD + k];
#pragma unroll
    for (int j = 0; j < 4; ++j)
      acc[j] = fmaf(proj_w[(i0 + j) * DD + n], won, acc[j]);
  }
#pragma unroll
  for (int j = 0; j < 4; ++j) Wc[(i0 + j) * DD + k] = (__hip_bfloat16)acc[j];

  __shared__ float red[256];
#pragma unroll
  for (int j = 0; j < 4; ++j) {
    red[k] = proj_w[(i0 + j) * DD + k] * out_b[k];
    __syncthreads();
    for (int sft = 128; sft > 0; sft >>= 1) {
      if (k < sft) red[k] += red[k + sft];
      __syncthreads();
    }
    if (k == 0) bc[i0 + j] = proj_b[i0 + j] + red[0];
    __syncthreads();
  }
}

// ---------------------------------------------------------------------------
// bf16 MFMA NT GEMM (m97 structure): C = A[M,K]_bf16 @ W[N,K]_bf16^T + epi.
// Fully-padded M-tiles ((r0&1023) >= lens[b]) are skipped: their outputs feed
// only padded rows, which the final epilogue zeroes. EPI=3 still writes zeros.
// EPI: 0 = +bias -> bf16; 1 = +bias,gelu -> bf16;
//      2 = +bias+resid(f32) -> f32 AND bf16; 3 = +bias+resid(f32),zero pad -> f32
// ---------------------------------------------------------------------------
template <int EPI, int BM>
__global__ __launch_bounds__(256) void gemm_bf16(
    const __hip_bfloat16* __restrict__ A, const __hip_bfloat16* __restrict__ W,
    const float* __restrict__ bias, const float* __restrict__ resid,
    float* __restrict__ Cf, __hip_bfloat16* __restrict__ Cb, const int M,
    const int N, const int K, const int* __restrict__ lens) {
  constexpr int MF = BM / 32;
  constexpr int CH = BM / 64;
  __shared__ __bf16 As[2][BM][32];
  __shared__ __bf16 Bs[2][128][32];

  const int tid = threadIdx.x;
  const int w = tid >> 6;
  const int lane = tid & 63;
  const int c = lane & 15;
  const int hq = lane >> 4;
  const int h8 = hq << 3;
  const int wr = w >> 1, wc = w & 1;
  const int c0 = blockIdx.x << 7;
  const int r0 = blockIdx.y * BM;

  // ---- padded-tile skip (tiles never straddle batches: BM | 1024) ----
  const int mylen = lens[r0 >> 10];
  if ((r0 & (LL - 1)) >= mylen) {
    if (EPI == 3) {
#pragma unroll
      for (int m = 0; m < MF; ++m)
#pragma unroll
        for (int i = 0; i < 4; ++i) {
          const int gr = r0 + wr * (MF * 16) + (m << 4) + (hq << 2) + i;
#pragma unroll
          for (int n = 0; n < 4; ++n) {
            const int gc = c0 + (wc << 6) + (n << 4) + c;
            Cf[(size_t)gr * N + gc] = 0.f;
          }
        }
    }
    return;
  }

  const int srow = tid >> 2;
  const int scol = (tid & 3) << 3;

  auto STAGE = [&](int buf, int kt) {
    const int k0 = kt << 5;
#pragma unroll
    for (int ch = 0; ch < CH; ++ch)
      gload16(A + (size_t)(r0 + (ch << 6) + srow) * K + k0 + scol,
              &As[buf][(ch << 6) + (w << 4)][0]);
#pragma unroll
    for (int ch = 0; ch < 2; ++ch)
      gload16(W + (size_t)(c0 + (ch << 6) + srow) * K + k0 + scol,
              &Bs[buf][(ch << 6) + (w << 4)][0]);
  };

  f32x4 acc[MF][4];
#pragma unroll
  for (int m = 0; m < MF; ++m)
#pragma unroll
    for (int n = 0; n < 4; ++n) acc[m][n] = (f32x4){0.f, 0.f, 0.f, 0.f};

  const int nkt = K >> 5;
  int buf = 0;
  STAGE(0, 0);
  __syncthreads();
  for (int kt = 0; kt < nkt; ++kt) {
    if (kt + 1 < nkt) STAGE(buf ^ 1, kt + 1);
    bf16x8 af[MF], bfr[4];
#pragma unroll
    for (int m = 0; m < MF; ++m)
      af[m] = *(const bf16x8*)&As[buf][wr * (MF * 16) + (m << 4) + c][h8];
#pragma unroll
    for (int n = 0; n < 4; ++n)
      bfr[n] = *(const bf16x8*)&Bs[buf][(wc << 6) + (n << 4) + c][h8];
#pragma unroll
    for (int m = 0; m < MF; ++m)
#pragma unroll
      for (int n = 0; n < 4; ++n)
        acc[m][n] =
            __builtin_amdgcn_mfma_f32_16x16x32_bf16(af[m], bfr[n], acc[m][n], 0, 0, 0);
    __syncthreads();
    buf ^= 1;
  }

  float bv[4];
#pragma unroll
  for (int n = 0; n < 4; ++n) bv[n] = bias[c0 + (wc << 6) + (n << 4) + c];

#pragma unroll
  for (int m = 0; m < MF; ++m) {
#pragma unroll
    for (int i = 0; i < 4; ++i) {
      const int gr = r0 + wr * (MF * 16) + (m << 4) + (hq << 2) + i;
      const bool zrow = (EPI == 3) && ((gr & (LL - 1)) >= mylen);
#pragma unroll
      for (int n = 0; n < 4; ++n) {
        const int gc = c0 + (wc << 6) + (n << 4) + c;
        float v = acc[m][n][i] + bv[n];
        if (EPI == 1) v = 0.5f * v * (1.0f + erff(v * 0.70710678118654752f));
        if (EPI >= 2) v += resid[(size_t)gr * N + gc];
        if (EPI == 3 && zrow) v = 0.f;
        if (EPI == 2 || EPI == 3) Cf[(size_t)gr * N + gc] = v;
        if (EPI != 3) Cb[(size_t)gr * N + gc] = (__hip_bfloat16)v;
      }
    }
  }
}

// ---------------------------------------------------------------------------
// MFMA bf16 flash attention, static-max softmax (m = 8, shift-invariant).
// Grid (L/64, H, B), 256 threads = 4 waves, wave w owns q rows [q0+16w, +16).
// setprio(1) around MFMA clusters (T5; independent blocks per CU -> phase
// diversity). K/V register-double-buffered; Vt stride 66 (conflict-free).
// ---------------------------------------------------------------------------
__global__ __launch_bounds__(256) void attn_fwd_mfma(
    const __hip_bfloat16* __restrict__ qkv, __hip_bfloat16* __restrict__ ctx,
    const int* __restrict__ lens) {
  __shared__ __bf16 Ks[64][56];
  __shared__ __bf16 Vt[32][66];
  __shared__ __bf16 Pl[4][16][72];

  const int tid = threadIdx.x;
  const int q0 = blockIdx.x << 6;
  const int hh = blockIdx.y;
  const int b = blockIdx.z;
  const int slen = lens[b];
  if (q0 >= slen) return;  // padded q rows are zeroed downstream

  const int w = tid >> 6;
  const int lane = tid & 63;
  const int c = lane & 15;
  const int h = lane >> 4;
  const int h8 = h << 3;

  const float L2E = 1.44269504f;
  const float sf = (float)slen;
  const float cb = -7.0f * L2E;          // (bias_const 1 - moff 8) * log2e
  const float cd = (1.0f / sf) * L2E;    // dist coefficient * log2e
  const float qscale = 0.17677669529663689f * L2E;  // 1/sqrt(32) * log2e

  bf16x8 qf;
  {
    const int qrow = q0 + (w << 4) + c;
    const bf16x8 qraw =
        *(const bf16x8*)(qkv + (size_t)(b * LL + qrow) * 768 + hh * DHH + h8);
#pragma unroll
    for (int j = 0; j < 8; ++j) qf[j] = (__bf16)((float)qraw[j] * qscale);
  }

  f32x4 acc0 = {0.f, 0.f, 0.f, 0.f};
  f32x4 acc1 = {0.f, 0.f, 0.f, 0.f};
  float lsum[4] = {0.f, 0.f, 0.f, 0.f};

  const int skey = tid >> 2;
  const int sdg = (tid & 3) << 3;
  const int ntk = (slen + 63) >> 6;
  const int qg = q0 + (w << 4) + (h << 2);

  bf16x8 kreg, vreg;
  {
    const __hip_bfloat16* kb =
        qkv + (size_t)(b * LL + skey) * 768 + 256 + hh * DHH + sdg;
    kreg = *(const bf16x8*)kb;
    vreg = *(const bf16x8*)(kb + 256);
  }

  for (int kt = 0; kt < ntk; ++kt) {
    const int kbase = kt << 6;
    __syncthreads();
    *(bf16x8*)&Ks[skey][sdg] = kreg;
#pragma unroll
    for (int j = 0; j < 8; ++j) Vt[sdg + j][skey] = vreg[j];
    if (kt + 1 < ntk) {
      const __hip_bfloat16* kb =
          qkv + (size_t)(b * LL + kbase + 64 + skey) * 768 + 256 + hh * DHH + sdg;
      kreg = *(const bf16x8*)kb;
      vreg = *(const bf16x8*)(kb + 256);
    }
    __syncthreads();

    // ---- QK^T: 4 MFMAs -> S*log2e [16q x 64k] ----
    f32x4 st[4];
    __builtin_amdgcn_s_setprio(1);
#pragma unroll
    for (int t = 0; t < 4; ++t) {
      const bf16x8 kf = *(const bf16x8*)&Ks[(t << 4) + c][h8];
      st[t] = __builtin_amdgcn_mfma_f32_16x16x32_bf16(
          qf, kf, (f32x4){0.f, 0.f, 0.f, 0.f}, 0, 0, 0);
    }
    __builtin_amdgcn_s_setprio(0);

    // ---- static-max softmax: p = exp2(S*l2e + cb - dist*cd) ----
#pragma unroll
    for (int t = 0; t < 4; ++t) {
      const int kj = kbase + (t << 4) + c;
      const bool kvalid = kj < slen;
      const float kjf = (float)kj;
#pragma unroll
      for (int i = 0; i < 4; ++i) {
        const float dist = fabsf((float)(qg + i) - kjf);
        const float arg = kvalid ? (st[t][i] + cb - dist * cd) : -1e30f;
        const float p = __builtin_amdgcn_exp2f(arg);
        lsum[i] += p;
        Pl[w][(h << 2) + i][c + (t << 4)] = (__bf16)p;
      }
    }

    asm volatile("s_waitcnt lgkmcnt(0)" ::: "memory");

    // ---- PV: ctx[16q x 32d] += P[16x64] * V[64x32] ----
    __builtin_amdgcn_s_setprio(1);
#pragma unroll
    for (int n = 0; n < 2; ++n) {
      const bf16x8 pf = *(const bf16x8*)&Pl[w][c][h8 + (n << 5)];
      const uint32_t* v0p = (const uint32_t*)&Vt[c][h8 + (n << 5)];
      const uint32_t* v1p = (const uint32_t*)&Vt[16 + c][h8 + (n << 5)];
      union { uint32_t u[4]; bf16x8 v; } t0, t1;
#pragma unroll
      for (int j = 0; j < 4; ++j) { t0.u[j] = v0p[j]; t1.u[j] = v1p[j]; }
      acc0 = __builtin_amdgcn_mfma_f32_16x16x32_bf16(pf, t0.v, acc0, 0, 0, 0);
      acc1 = __builtin_amdgcn_mfma_f32_16x16x32_bf16(pf, t1.v, acc1, 0, 0, 0);
    }
    __builtin_amdgcn_s_setprio(0);
  }

  // ---- final l reduction (once) + epilogue ----
#pragma unroll
  for (int i = 0; i < 4; ++i) {
    float l = lsum[i];
    l += __shfl_xor(l, 1);
    l += __shfl_xor(l, 2);
    l += __shfl_xor(l, 4);
    l += __shfl_xor(l, 8);
    const float il = 1.0f / l;
    __hip_bfloat16* op =
        ctx + (size_t)(b * LL + q0 + (w << 4) + (h << 2) + i) * 256 + hh * DHH;
    op[c] = (__hip_bfloat16)(acc0[i] * il);
    op[c + 16] = (__hip_bfloat16)(acc1[i] * il);
  }
}

// ---------------------------------------------------------------------------
extern "C" void kernel_launch(void* const* d_in, const int* in_sizes, int n_in,
                              void* d_out, int out_size, void* d_ws,
                              size_t ws_size, hipStream_t stream) {
  (void)in_sizes; (void)n_in; (void)out_size; (void)ws_size;
  const float* src = (const float*)d_in[0];
  const unsigned char* mask = (const unsigned char*)d_in[1];
  const float* in_proj_w = (const float*)d_in[2];
  const float* in_proj_b = (const float*)d_in[3];
  const float* out_w = (const float*)d_in[4];
  const float* out_b = (const float*)d_in[5];
  const float* proj_w = (const float*)d_in[6];
  const float* proj_b = (const float*)d_in[7];
  const float* ff1_w = (const float*)d_in[8];
  const float* ff1_b = (const float*)d_in[9];
  const float* ff2_w = (const float*)d_in[10];
  const float* ff2_b = (const float*)d_in[11];
  float* out = (float*)d_out;

  const int M = BB * LL;  // 8192
  char* p = (char*)d_ws;
  __hip_bfloat16* qkv_bf = (__hip_bfloat16*)p; p += (size_t)M * 768 * 2;
  __hip_bfloat16* ctx_bf = (__hip_bfloat16*)p; p += (size_t)M * 256 * 2;
  float* hbuf_f = (float*)p;                   p += (size_t)M * 256 * 4;
  __hip_bfloat16* hbuf_bf = (__hip_bfloat16*)p; p += (size_t)M * 256 * 2;
  __hip_bfloat16* ff1o_bf = (__hip_bfloat16*)p; p += (size_t)M * 2048 * 2;
  __hip_bfloat16* src_bf = (__hip_bfloat16*)p;  p += (size_t)M * 256 * 2;
  __hip_bfloat16* wqkv_bf = (__hip_bfloat16*)p; p += (size_t)768 * 256 * 2;
  __hip_bfloat16* wff1_bf = (__hip_bfloat16*)p; p += (size_t)2048 * 256 * 2;
  __hip_bfloat16* wff2_bf = (__hip_bfloat16*)p; p += (size_t)256 * 2048 * 2;
  __hip_bfloat16* wc_bf = (__hip_bfloat16*)p;   p += (size_t)256 * 256 * 2;
  float* bc = (float*)p;                        p += 256 * 4;
  int* lens = (int*)p;

  compute_lens_kernel<<<1, 256, 0, stream>>>(mask, lens);
  {
    const int n0 = M * 256, n1 = 768 * 256, n2 = 2048 * 256, n3 = 256 * 2048;
    const int nb = (n0 + n1 + n2 + n3) / 8 / 256;
    cvt4_kernel<<<nb, 256, 0, stream>>>(src, src_bf, n0, in_proj_w, wqkv_bf, n1,
                                        ff1_w, wff1_bf, n2, ff2_w, wff2_bf, n3);
  }
  wc_kernel<<<64, 256, 0, stream>>>(proj_w, out_w, proj_b, out_b, wc_bf, bc);

  // qkv = src @ in_proj^T + b   [8192 x 768], bf16 out
  gemm_bf16<0, 128><<<dim3(6, 64), 256, 0, stream>>>(
      src_bf, wqkv_bf, in_proj_b, nullptr, nullptr, qkv_bf, M, 768, 256, lens);
  // attention
  attn_fwd_mfma<<<dim3(LL / 64, HHN, BB), 256, 0, stream>>>(qkv_bf, ctx_bf, lens);
  // hbuf = src + ctx @ Wc^T + bc   [8192 x 256], f32 + bf16 out
  gemm_bf16<2, 64><<<dim3(2, 128), 256, 0, stream>>>(
      ctx_bf, wc_bf, bc, src, hbuf_f, hbuf_bf, M, 256, 256, lens);
  // ff1o = gelu(hbuf @ ff1^T + b)  [8192 x 2048], bf16 out
  gemm_bf16<1, 128><<<dim3(16, 64), 256, 0, stream>>>(
      hbuf_bf, wff1_bf, ff1_b, nullptr, nullptr, ff1o_bf, M, 2048, 256, lens);
  // out = hbuf + ff1o @ ff2^T + b, zero padded rows  [8192 x 256], f32 out
  gemm_bf16<3, 64><<<dim3(2, 128), 256, 0, stream>>>(
      ff1o_bf, wff2_bf, ff2_b, hbuf_f, out, nullptr, M, 256, 2048, lens);
}

// Round 7
// 129.659 us; speedup vs baseline: 1.2092x; 1.2092x over previous
//
#include <hip/hip_runtime.h>
#include <hip/hip_bf16.h>

// DeepPM Transformer encoder layer (round 6 = round 5 with the compile fix).
// - preamble (lens + fp32->bf16 cvt + fused proj@out weight) in ONE kernel
// - split-K x4 FF2 (K=2048 was a 64-iter serial latency chain at 1 block/CU)
//   + float4 reduce kernel fused with residual/bias/zero-padded-rows
// - attention: LDS double-buffered K/V -> 1 barrier per 64-key tile, stage
//   overlapped with compute; static-max softmax; setprio on MFMA clusters
// B=8, L=1024, D=256, H=8 (DH=32), DFF=2048.

#define BB   8
#define LL   1024
#define DD   256
#define HHN  8
#define DHH  32
#define DFFN 2048

typedef __attribute__((ext_vector_type(8))) __bf16 bf16x8;
typedef __attribute__((ext_vector_type(4))) float f32x4;

__device__ inline void gload16(const void* g, void* l) {
  __builtin_amdgcn_global_load_lds(
      (const __attribute__((address_space(1))) void*)g,
      (__attribute__((address_space(3))) void*)l, 16, 0, 0);
}

// ---------------------------------------------------------------------------
// Preamble (one kernel, role by blockIdx):
//  blocks [0,1632):    cvt fp32->bf16 of {src, in_proj_w, ff1_w, ff2_w}
//  block 1632:         lens[b] from mask (format auto-detect)
//  blocks [1633,1697): Wc = proj_w@out_w (bf16), bc = proj_b + proj_w@out_b
// ---------------------------------------------------------------------------
#define NCVT0 (BB * LL * DD)      // 2097152
#define NCVT1 (768 * DD)          // 196608
#define NCVT2 (DFFN * DD)         // 524288
#define NCVT3 (DD * DFFN)         // 524288
#define NB_CVT ((NCVT0 + NCVT1 + NCVT2 + NCVT3) / 2048)  // 1632

__global__ __launch_bounds__(256) void preamble_kernel(
    const float* __restrict__ src, const unsigned char* __restrict__ mb,
    const float* __restrict__ in_proj_w, const float* __restrict__ ff1_w,
    const float* __restrict__ ff2_w, const float* __restrict__ proj_w,
    const float* __restrict__ out_w, const float* __restrict__ proj_b,
    const float* __restrict__ out_b, __hip_bfloat16* __restrict__ src_bf,
    __hip_bfloat16* __restrict__ wqkv_bf, __hip_bfloat16* __restrict__ wff1_bf,
    __hip_bfloat16* __restrict__ wff2_bf, __hip_bfloat16* __restrict__ wc_bf,
    float* __restrict__ bc, int* __restrict__ lens) {
  const int bid = blockIdx.x;
  const int tid = threadIdx.x;
  __shared__ float red[256];
  __shared__ int cnt[BB];
  __shared__ int flag3f, flagNA;

  if (bid < NB_CVT) {
    // ---- conversion (block ranges align with array boundaries) ----
    int i = bid * 2048 + tid * 8;
    const float* s;
    __hip_bfloat16* d;
    if (i < NCVT0) { s = src; d = src_bf; }
    else if (i < NCVT0 + NCVT1) { s = in_proj_w; d = wqkv_bf; i -= NCVT0; }
    else if (i < NCVT0 + NCVT1 + NCVT2) { s = ff1_w; d = wff1_bf; i -= NCVT0 + NCVT1; }
    else { s = ff2_w; d = wff2_bf; i -= NCVT0 + NCVT1 + NCVT2; }
    const float4 a = *(const float4*)(s + i);
    const float4 b = *(const float4*)(s + i + 4);
    bf16x8 o;
    o[0] = (__bf16)a.x; o[1] = (__bf16)a.y; o[2] = (__bf16)a.z; o[3] = (__bf16)a.w;
    o[4] = (__bf16)b.x; o[5] = (__bf16)b.y; o[6] = (__bf16)b.z; o[7] = (__bf16)b.w;
    *(bf16x8*)(d + i) = o;
  } else if (bid == NB_CVT) {
    // ---- lens ----
    if (tid == 0) { flag3f = 0; flagNA = 0; }
    if (tid < BB) cnt[tid] = 0;
    __syncthreads();
    for (int i = tid; i < BB * LL; i += 256) {
      unsigned char v = mb[i];
      if (v) {
        if ((i & 3) == 3 && v == 0x3F) flag3f = 1;
        else if (i & 3) flagNA = 1;
      }
    }
    __syncthreads();
    const bool isfloat = (flag3f != 0);
    const bool isbool = (!isfloat) && (flagNA != 0);
    if (isbool) {
      for (int i = tid; i < BB * LL; i += 256)
        if (mb[i] == 0) atomicAdd(&cnt[i >> 10], 1);
    } else {
      const int* mi = (const int*)mb;
      for (int i = tid; i < BB * LL; i += 256)
        if (mi[i] == 0) atomicAdd(&cnt[i >> 10], 1);
    }
    __syncthreads();
    if (tid < BB) lens[tid] = cnt[tid];
  } else {
    // ---- Wc / bc: 4 rows per block ----
    const int i0 = (bid - NB_CVT - 1) << 2;
    const int k = tid;
    float acc[4] = {0.f, 0.f, 0.f, 0.f};
    for (int n = 0; n < DD; ++n) {
      const float won = out_w[n * DD + k];
#pragma unroll
      for (int j = 0; j < 4; ++j)
        acc[j] = fmaf(proj_w[(i0 + j) * DD + n], won, acc[j]);
    }
#pragma unroll
    for (int j = 0; j < 4; ++j) wc_bf[(i0 + j) * DD + k] = (__hip_bfloat16)acc[j];
#pragma unroll
    for (int j = 0; j < 4; ++j) {
      red[k] = proj_w[(i0 + j) * DD + k] * out_b[k];
      __syncthreads();
      for (int sft = 128; sft > 0; sft >>= 1) {
        if (k < sft) red[k] += red[k + sft];
        __syncthreads();
      }
      if (k == 0) bc[i0 + j] = proj_b[i0 + j] + red[0];
      __syncthreads();
    }
  }
}

// ---------------------------------------------------------------------------
// bf16 MFMA NT GEMM (m97 structure): C = A[M,K]_bf16 @ W[N,K]_bf16^T + epi.
// Fully-padded M-tiles skipped (outputs feed only padded rows).
// EPI: 0 = +bias -> bf16; 1 = +bias,gelu -> bf16; 2 = +bias+resid(f32) -> f32+bf16
// ---------------------------------------------------------------------------
template <int EPI, int BM>
__global__ __launch_bounds__(256) void gemm_bf16(
    const __hip_bfloat16* __restrict__ A, const __hip_bfloat16* __restrict__ W,
    const float* __restrict__ bias, const float* __restrict__ resid,
    float* __restrict__ Cf, __hip_bfloat16* __restrict__ Cb, const int M,
    const int N, const int K, const int* __restrict__ lens) {
  constexpr int MF = BM / 32;
  constexpr int CH = BM / 64;
  __shared__ __bf16 As[2][BM][32];
  __shared__ __bf16 Bs[2][128][32];

  const int tid = threadIdx.x;
  const int w = tid >> 6;
  const int lane = tid & 63;
  const int c = lane & 15;
  const int hq = lane >> 4;
  const int h8 = hq << 3;
  const int wr = w >> 1, wc = w & 1;
  const int c0 = blockIdx.x << 7;
  const int r0 = blockIdx.y * BM;

  const int mylen = lens[r0 >> 10];
  if ((r0 & (LL - 1)) >= mylen) return;  // dead tile

  const int srow = tid >> 2;
  const int scol = (tid & 3) << 3;

  auto STAGE = [&](int buf, int kt) {
    const int k0 = kt << 5;
#pragma unroll
    for (int ch = 0; ch < CH; ++ch)
      gload16(A + (size_t)(r0 + (ch << 6) + srow) * K + k0 + scol,
              &As[buf][(ch << 6) + (w << 4)][0]);
#pragma unroll
    for (int ch = 0; ch < 2; ++ch)
      gload16(W + (size_t)(c0 + (ch << 6) + srow) * K + k0 + scol,
              &Bs[buf][(ch << 6) + (w << 4)][0]);
  };

  f32x4 acc[MF][4];
#pragma unroll
  for (int m = 0; m < MF; ++m)
#pragma unroll
    for (int n = 0; n < 4; ++n) acc[m][n] = (f32x4){0.f, 0.f, 0.f, 0.f};

  const int nkt = K >> 5;
  int buf = 0;
  STAGE(0, 0);
  __syncthreads();
  for (int kt = 0; kt < nkt; ++kt) {
    if (kt + 1 < nkt) STAGE(buf ^ 1, kt + 1);
    bf16x8 af[MF], bfr[4];
#pragma unroll
    for (int m = 0; m < MF; ++m)
      af[m] = *(const bf16x8*)&As[buf][wr * (MF * 16) + (m << 4) + c][h8];
#pragma unroll
    for (int n = 0; n < 4; ++n)
      bfr[n] = *(const bf16x8*)&Bs[buf][(wc << 6) + (n << 4) + c][h8];
#pragma unroll
    for (int m = 0; m < MF; ++m)
#pragma unroll
      for (int n = 0; n < 4; ++n)
        acc[m][n] =
            __builtin_amdgcn_mfma_f32_16x16x32_bf16(af[m], bfr[n], acc[m][n], 0, 0, 0);
    __syncthreads();
    buf ^= 1;
  }

  float bv[4];
#pragma unroll
  for (int n = 0; n < 4; ++n) bv[n] = bias[c0 + (wc << 6) + (n << 4) + c];

#pragma unroll
  for (int m = 0; m < MF; ++m) {
#pragma unroll
    for (int i = 0; i < 4; ++i) {
      const int gr = r0 + wr * (MF * 16) + (m << 4) + (hq << 2) + i;
#pragma unroll
      for (int n = 0; n < 4; ++n) {
        const int gc = c0 + (wc << 6) + (n << 4) + c;
        float v = acc[m][n][i] + bv[n];
        if (EPI == 1) v = 0.5f * v * (1.0f + erff(v * 0.70710678118654752f));
        if (EPI == 2) {
          v += resid[(size_t)gr * N + gc];
          Cf[(size_t)gr * N + gc] = v;
        }
        Cb[(size_t)gr * N + gc] = (__hip_bfloat16)v;
      }
    }
  }
}

// ---------------------------------------------------------------------------
// FF2 split-K partial: P[z][M][256] = A[M, z*512:(z+1)*512] @ W[:, same]^T
// BM=64, BN=128, 16 K-iters per block. Padded tiles skipped (reduce zeroes).
// ---------------------------------------------------------------------------
__global__ __launch_bounds__(256) void gemm_ff2_part(
    const __hip_bfloat16* __restrict__ A, const __hip_bfloat16* __restrict__ W,
    float* __restrict__ P, const int* __restrict__ lens) {
  constexpr int MF = 2;
  __shared__ __bf16 As[2][64][32];
  __shared__ __bf16 Bs[2][128][32];

  const int tid = threadIdx.x;
  const int w = tid >> 6;
  const int lane = tid & 63;
  const int c = lane & 15;
  const int hq = lane >> 4;
  const int h8 = hq << 3;
  const int wr = w >> 1, wc = w & 1;
  const int c0 = blockIdx.x << 7;
  const int r0 = blockIdx.y << 6;
  if ((r0 & (LL - 1)) >= lens[r0 >> 10]) return;

  const int kz = blockIdx.z;
  const int kbase = kz << 9;  // *512
  const int srow = tid >> 2;
  const int scol = (tid & 3) << 3;

  auto STAGE = [&](int buf, int kt) {
    const int k0 = kbase + (kt << 5);
    gload16(A + (size_t)(r0 + srow) * DFFN + k0 + scol, &As[buf][w << 4][0]);
#pragma unroll
    for (int ch = 0; ch < 2; ++ch)
      gload16(W + (size_t)(c0 + (ch << 6) + srow) * DFFN + k0 + scol,
              &Bs[buf][(ch << 6) + (w << 4)][0]);
  };

  f32x4 acc[MF][4];
#pragma unroll
  for (int m = 0; m < MF; ++m)
#pragma unroll
    for (int n = 0; n < 4; ++n) acc[m][n] = (f32x4){0.f, 0.f, 0.f, 0.f};

  int buf = 0;
  STAGE(0, 0);
  __syncthreads();
  for (int kt = 0; kt < 16; ++kt) {
    if (kt + 1 < 16) STAGE(buf ^ 1, kt + 1);
    bf16x8 af[MF], bfr[4];
#pragma unroll
    for (int m = 0; m < MF; ++m)
      af[m] = *(const bf16x8*)&As[buf][wr * (MF * 16) + (m << 4) + c][h8];
#pragma unroll
    for (int n = 0; n < 4; ++n)
      bfr[n] = *(const bf16x8*)&Bs[buf][(wc << 6) + (n << 4) + c][h8];
#pragma unroll
    for (int m = 0; m < MF; ++m)
#pragma unroll
      for (int n = 0; n < 4; ++n)
        acc[m][n] =
            __builtin_amdgcn_mfma_f32_16x16x32_bf16(af[m], bfr[n], acc[m][n], 0, 0, 0);
    __syncthreads();
    buf ^= 1;
  }

  float* Pz = P + (size_t)kz * (BB * LL) * DD;
#pragma unroll
  for (int m = 0; m < MF; ++m)
#pragma unroll
    for (int i = 0; i < 4; ++i) {
      const int gr = r0 + wr * (MF * 16) + (m << 4) + (hq << 2) + i;
#pragma unroll
      for (int n = 0; n < 4; ++n)
        Pz[(size_t)gr * DD + c0 + (wc << 6) + (n << 4) + c] = acc[m][n][i];
    }
}

// ---------------------------------------------------------------------------
// FF2 reduce: out = resid + bias + sum_z P[z], zero padded rows. float4/thread.
// ---------------------------------------------------------------------------
__global__ __launch_bounds__(256) void ff2_reduce(
    const float* __restrict__ P, const float* __restrict__ resid,
    const float* __restrict__ bias, float* __restrict__ out,
    const int* __restrict__ lens) {
  const int idx = blockIdx.x * 256 + threadIdx.x;  // one float4
  const int r = idx >> 6;
  const int c4 = (idx & 63) << 2;
  float4 o;
  if ((r & (LL - 1)) >= lens[r >> 10]) {
    o.x = o.y = o.z = o.w = 0.f;
  } else {
    const size_t base = (size_t)r * DD + c4;
    o = *(const float4*)&resid[base];
    const float4 bv = *(const float4*)&bias[c4];
    o.x += bv.x; o.y += bv.y; o.z += bv.z; o.w += bv.w;
#pragma unroll
    for (int z = 0; z < 4; ++z) {
      const float4 pv = *(const float4*)&P[(size_t)z * (BB * LL) * DD + base];
      o.x += pv.x; o.y += pv.y; o.z += pv.z; o.w += pv.w;
    }
  }
  *(float4*)&out[(size_t)r * DD + c4] = o;
}

// ---------------------------------------------------------------------------
// MFMA bf16 flash attention, static-max softmax (shift-invariant, m=8),
// LDS double-buffered K/V (ONE barrier per 64-key tile; stage overlapped with
// compute of the other buffer). Vt stride 66 (conflict-free transpose).
// ---------------------------------------------------------------------------
__global__ __launch_bounds__(256) void attn_fwd_mfma(
    const __hip_bfloat16* __restrict__ qkv, __hip_bfloat16* __restrict__ ctx,
    const int* __restrict__ lens) {
  __shared__ __bf16 Ks[2][64][56];
  __shared__ __bf16 Vt[2][32][66];
  __shared__ __bf16 Pl[4][16][72];

  const int tid = threadIdx.x;
  const int q0 = blockIdx.x << 6;
  const int hh = blockIdx.y;
  const int b = blockIdx.z;
  const int slen = lens[b];
  if (q0 >= slen) return;  // padded q rows are zeroed downstream

  const int w = tid >> 6;
  const int lane = tid & 63;
  const int c = lane & 15;
  const int h = lane >> 4;
  const int h8 = h << 3;

  const float L2E = 1.44269504f;
  const float sf = (float)slen;
  const float cb = -7.0f * L2E;        // (bias_const 1 - moff 8) * log2e
  const float cd = (1.0f / sf) * L2E;  // dist coefficient * log2e
  const float qscale = 0.17677669529663689f * L2E;

  bf16x8 qf;
  {
    const int qrow = q0 + (w << 4) + c;
    const bf16x8 qraw =
        *(const bf16x8*)(qkv + (size_t)(b * LL + qrow) * 768 + hh * DHH + h8);
#pragma unroll
    for (int j = 0; j < 8; ++j) qf[j] = (__bf16)((float)qraw[j] * qscale);
  }

  f32x4 acc0 = {0.f, 0.f, 0.f, 0.f};
  f32x4 acc1 = {0.f, 0.f, 0.f, 0.f};
  float lsum[4] = {0.f, 0.f, 0.f, 0.f};

  const int skey = tid >> 2;
  const int sdg = (tid & 3) << 3;
  const int ntk = (slen + 63) >> 6;
  const int qg = q0 + (w << 4) + (h << 2);

  const __hip_bfloat16* kvbase = qkv + (size_t)b * LL * 768 + 256 + hh * DHH + sdg;

  // prologue: stage tile 0 into buf0; preload tile 1 regs
  bf16x8 kreg, vreg;
  {
    const __hip_bfloat16* kb = kvbase + (size_t)skey * 768;
    kreg = *(const bf16x8*)kb;
    vreg = *(const bf16x8*)(kb + 256);
    *(bf16x8*)&Ks[0][skey][sdg] = kreg;
#pragma unroll
    for (int j = 0; j < 8; ++j) Vt[0][sdg + j][skey] = vreg[j];
  }
  if (ntk > 1) {
    const __hip_bfloat16* kb = kvbase + (size_t)(64 + skey) * 768;
    kreg = *(const bf16x8*)kb;
    vreg = *(const bf16x8*)(kb + 256);
  }
  __syncthreads();

  for (int kt = 0; kt < ntk; ++kt) {
    const int p = kt & 1;
    const int kbase = kt << 6;

    // ---- QK^T: 4 MFMAs -> S*log2e [16q x 64k] ----
    f32x4 st[4];
    __builtin_amdgcn_s_setprio(1);
#pragma unroll
    for (int t = 0; t < 4; ++t) {
      const bf16x8 kf = *(const bf16x8*)&Ks[p][(t << 4) + c][h8];
      st[t] = __builtin_amdgcn_mfma_f32_16x16x32_bf16(
          qf, kf, (f32x4){0.f, 0.f, 0.f, 0.f}, 0, 0, 0);
    }
    __builtin_amdgcn_s_setprio(0);

    // ---- static-max softmax: p = exp2(S*l2e + cb - dist*cd) ----
#pragma unroll
    for (int t = 0; t < 4; ++t) {
      const int kj = kbase + (t << 4) + c;
      const bool kvalid = kj < slen;
      const float kjf = (float)kj;
#pragma unroll
      for (int i = 0; i < 4; ++i) {
        const float dist = fabsf((float)(qg + i) - kjf);
        const float arg = kvalid ? (st[t][i] + cb - dist * cd) : -1e30f;
        const float pv = __builtin_amdgcn_exp2f(arg);
        lsum[i] += pv;
        Pl[w][(h << 2) + i][c + (t << 4)] = (__bf16)pv;
      }
    }

    asm volatile("s_waitcnt lgkmcnt(0)" ::: "memory");

    // ---- PV: ctx[16q x 32d] += P[16x64] * V[64x32] ----
    __builtin_amdgcn_s_setprio(1);
#pragma unroll
    for (int n = 0; n < 2; ++n) {
      const bf16x8 pf = *(const bf16x8*)&Pl[w][c][h8 + (n << 5)];
      const uint32_t* v0p = (const uint32_t*)&Vt[p][c][h8 + (n << 5)];
      const uint32_t* v1p = (const uint32_t*)&Vt[p][16 + c][h8 + (n << 5)];
      union { uint32_t u[4]; bf16x8 v; } t0, t1;
#pragma unroll
      for (int j = 0; j < 4; ++j) { t0.u[j] = v0p[j]; t1.u[j] = v1p[j]; }
      acc0 = __builtin_amdgcn_mfma_f32_16x16x32_bf16(pf, t0.v, acc0, 0, 0, 0);
      acc1 = __builtin_amdgcn_mfma_f32_16x16x32_bf16(pf, t1.v, acc1, 0, 0, 0);
    }
    __builtin_amdgcn_s_setprio(0);

    // ---- stage next tile into the other buffer; prefetch tile kt+2 ----
    if (kt + 1 < ntk) {
      *(bf16x8*)&Ks[p ^ 1][skey][sdg] = kreg;
#pragma unroll
      for (int j = 0; j < 8; ++j) Vt[p ^ 1][sdg + j][skey] = vreg[j];
      if (kt + 2 < ntk) {
        const __hip_bfloat16* kb = kvbase + (size_t)(((kt + 2) << 6) + skey) * 768;
        kreg = *(const bf16x8*)kb;
        vreg = *(const bf16x8*)(kb + 256);
      }
    }
    __syncthreads();
  }

  // ---- final l reduction + epilogue ----
#pragma unroll
  for (int i = 0; i < 4; ++i) {
    float l = lsum[i];
    l += __shfl_xor(l, 1);
    l += __shfl_xor(l, 2);
    l += __shfl_xor(l, 4);
    l += __shfl_xor(l, 8);
    const float il = 1.0f / l;
    __hip_bfloat16* op =
        ctx + (size_t)(b * LL + q0 + (w << 4) + (h << 2) + i) * 256 + hh * DHH;
    op[c] = (__hip_bfloat16)(acc0[i] * il);
    op[c + 16] = (__hip_bfloat16)(acc1[i] * il);
  }
}

// ---------------------------------------------------------------------------
extern "C" void kernel_launch(void* const* d_in, const int* in_sizes, int n_in,
                              void* d_out, int out_size, void* d_ws,
                              size_t ws_size, hipStream_t stream) {
  (void)in_sizes; (void)n_in; (void)out_size; (void)ws_size;
  const float* src = (const float*)d_in[0];
  const unsigned char* mask = (const unsigned char*)d_in[1];
  const float* in_proj_w = (const float*)d_in[2];
  const float* in_proj_b = (const float*)d_in[3];
  const float* out_w = (const float*)d_in[4];
  const float* out_b = (const float*)d_in[5];
  const float* proj_w = (const float*)d_in[6];
  const float* proj_b = (const float*)d_in[7];
  const float* ff1_w = (const float*)d_in[8];
  const float* ff1_b = (const float*)d_in[9];
  const float* ff2_w = (const float*)d_in[10];
  const float* ff2_b = (const float*)d_in[11];
  float* out = (float*)d_out;

  const int M = BB * LL;  // 8192
  char* p = (char*)d_ws;
  __hip_bfloat16* qkv_bf = (__hip_bfloat16*)p; p += (size_t)M * 768 * 2;
  __hip_bfloat16* ctx_bf = (__hip_bfloat16*)p; p += (size_t)M * 256 * 2;
  float* hbuf_f = (float*)p;                   p += (size_t)M * 256 * 4;
  __hip_bfloat16* hbuf_bf = (__hip_bfloat16*)p; p += (size_t)M * 256 * 2;
  __hip_bfloat16* ff1o_bf = (__hip_bfloat16*)p; p += (size_t)M * 2048 * 2;
  __hip_bfloat16* src_bf = (__hip_bfloat16*)p;  p += (size_t)M * 256 * 2;
  __hip_bfloat16* wqkv_bf = (__hip_bfloat16*)p; p += (size_t)768 * 256 * 2;
  __hip_bfloat16* wff1_bf = (__hip_bfloat16*)p; p += (size_t)2048 * 256 * 2;
  __hip_bfloat16* wff2_bf = (__hip_bfloat16*)p; p += (size_t)256 * 2048 * 2;
  __hip_bfloat16* wc_bf = (__hip_bfloat16*)p;   p += (size_t)256 * 256 * 2;
  float* bc = (float*)p;                        p += 256 * 4;
  int* lens = (int*)p;                          p += 256;  // aligned chunk
  float* pbuf = (float*)p;                      p += (size_t)4 * M * 256 * 4;

  // preamble: lens + cvt + fused weight (one kernel)
  preamble_kernel<<<NB_CVT + 1 + 64, 256, 0, stream>>>(
      src, mask, in_proj_w, ff1_w, ff2_w, proj_w, out_w, proj_b, out_b, src_bf,
      wqkv_bf, wff1_bf, wff2_bf, wc_bf, bc, lens);

  // qkv = src @ in_proj^T + b   [8192 x 768], bf16 out
  gemm_bf16<0, 128><<<dim3(6, 64), 256, 0, stream>>>(
      src_bf, wqkv_bf, in_proj_b, nullptr, nullptr, qkv_bf, M, 768, 256, lens);
  // attention
  attn_fwd_mfma<<<dim3(LL / 64, HHN, BB), 256, 0, stream>>>(qkv_bf, ctx_bf, lens);
  // hbuf = src + ctx @ Wc^T + bc   [8192 x 256], f32 + bf16 out
  gemm_bf16<2, 64><<<dim3(2, 128), 256, 0, stream>>>(
      ctx_bf, wc_bf, bc, src, hbuf_f, hbuf_bf, M, 256, 256, lens);
  // ff1o = gelu(hbuf @ ff1^T + b)  [8192 x 2048], bf16 out
  gemm_bf16<1, 128><<<dim3(16, 64), 256, 0, stream>>>(
      hbuf_bf, wff1_bf, ff1_b, nullptr, nullptr, ff1o_bf, M, 2048, 256, lens);
  // FF2 split-K x4 partials, then reduce (+resid +bias, zero padded rows)
  gemm_ff2_part<<<dim3(2, 128, 4), 256, 0, stream>>>(ff1o_bf, wff2_bf, pbuf, lens);
  ff2_reduce<<<M * 256 / 4 / 256, 256, 0, stream>>>(pbuf, hbuf_f, ff2_b, out, lens);
}

// Round 8
// 126.282 us; speedup vs baseline: 1.2415x; 1.0267x over previous
//
#include <hip/hip_runtime.h>
#include <hip/hip_bf16.h>

// DeepPM Transformer encoder layer (round 8): bf16 MFMA everywhere.
// - QKV GEMM reg-stages A/B directly from fp32 (cvt fused into staging) ->
//   src_bf / wqkv_bf eliminated, preamble shrunk to {ff1_w, ff2_w, wc, lens}
// - FF2 split-K x4 with bf16 partials (halved reduce traffic)
// - attention: LDS dbuf K/V, static-max softmax, full-tile fast path, setprio
// B=8, L=1024, D=256, H=8 (DH=32), DFF=2048.

#define BB   8
#define LL   1024
#define DD   256
#define HHN  8
#define DHH  32
#define DFFN 2048

typedef __attribute__((ext_vector_type(8))) __bf16 bf16x8;
typedef __attribute__((ext_vector_type(4))) float f32x4;

__device__ inline void gload16(const void* g, void* l) {
  __builtin_amdgcn_global_load_lds(
      (const __attribute__((address_space(1))) void*)g,
      (__attribute__((address_space(3))) void*)l, 16, 0, 0);
}

__device__ inline bf16x8 cvt8(const float4 a, const float4 b) {
  bf16x8 o;
  o[0] = (__bf16)a.x; o[1] = (__bf16)a.y; o[2] = (__bf16)a.z; o[3] = (__bf16)a.w;
  o[4] = (__bf16)b.x; o[5] = (__bf16)b.y; o[6] = (__bf16)b.z; o[7] = (__bf16)b.w;
  return o;
}

// ---------------------------------------------------------------------------
// Preamble (one kernel, role by blockIdx):
//  blocks [0,512):   cvt fp32->bf16 of {ff1_w, ff2_w}
//  block 512:        lens[b] from mask (format auto-detect)
//  blocks [513,577): Wc = proj_w@out_w (bf16), bc = proj_b + proj_w@out_b
// ---------------------------------------------------------------------------
#define NCVT2 (DFFN * DD)  // 524288
#define NCVT3 (DD * DFFN)  // 524288
#define NB_CVT ((NCVT2 + NCVT3) / 2048)  // 512

__global__ __launch_bounds__(256) void preamble_kernel(
    const unsigned char* __restrict__ mb, const float* __restrict__ ff1_w,
    const float* __restrict__ ff2_w, const float* __restrict__ proj_w,
    const float* __restrict__ out_w, const float* __restrict__ proj_b,
    const float* __restrict__ out_b, __hip_bfloat16* __restrict__ wff1_bf,
    __hip_bfloat16* __restrict__ wff2_bf, __hip_bfloat16* __restrict__ wc_bf,
    float* __restrict__ bc, int* __restrict__ lens) {
  const int bid = blockIdx.x;
  const int tid = threadIdx.x;
  __shared__ float red[256];
  __shared__ int cnt[BB];
  __shared__ int flag3f, flagNA;

  if (bid < NB_CVT) {
    int i = bid * 2048 + tid * 8;
    const float* s;
    __hip_bfloat16* d;
    if (i < NCVT2) { s = ff1_w; d = wff1_bf; }
    else { s = ff2_w; d = wff2_bf; i -= NCVT2; }
    const float4 a = *(const float4*)(s + i);
    const float4 b = *(const float4*)(s + i + 4);
    *(bf16x8*)(d + i) = cvt8(a, b);
  } else if (bid == NB_CVT) {
    if (tid == 0) { flag3f = 0; flagNA = 0; }
    if (tid < BB) cnt[tid] = 0;
    __syncthreads();
    for (int i = tid; i < BB * LL; i += 256) {
      unsigned char v = mb[i];
      if (v) {
        if ((i & 3) == 3 && v == 0x3F) flag3f = 1;
        else if (i & 3) flagNA = 1;
      }
    }
    __syncthreads();
    const bool isfloat = (flag3f != 0);
    const bool isbool = (!isfloat) && (flagNA != 0);
    if (isbool) {
      for (int i = tid; i < BB * LL; i += 256)
        if (mb[i] == 0) atomicAdd(&cnt[i >> 10], 1);
    } else {
      const int* mi = (const int*)mb;
      for (int i = tid; i < BB * LL; i += 256)
        if (mi[i] == 0) atomicAdd(&cnt[i >> 10], 1);
    }
    __syncthreads();
    if (tid < BB) lens[tid] = cnt[tid];
  } else {
    const int i0 = (bid - NB_CVT - 1) << 2;
    const int k = tid;
    float acc[4] = {0.f, 0.f, 0.f, 0.f};
    for (int n = 0; n < DD; ++n) {
      const float won = out_w[n * DD + k];
#pragma unroll
      for (int j = 0; j < 4; ++j)
        acc[j] = fmaf(proj_w[(i0 + j) * DD + n], won, acc[j]);
    }
#pragma unroll
    for (int j = 0; j < 4; ++j) wc_bf[(i0 + j) * DD + k] = (__hip_bfloat16)acc[j];
#pragma unroll
    for (int j = 0; j < 4; ++j) {
      red[k] = proj_w[(i0 + j) * DD + k] * out_b[k];
      __syncthreads();
      for (int sft = 128; sft > 0; sft >>= 1) {
        if (k < sft) red[k] += red[k + sft];
        __syncthreads();
      }
      if (k == 0) bc[i0 + j] = proj_b[i0 + j] + red[0];
      __syncthreads();
    }
  }
}

// ---------------------------------------------------------------------------
// QKV GEMM with fused fp32->bf16 staging: qkv = src @ in_proj^T + b (bf16 out).
// A and W read as fp32, converted in-register, ds_written to bf16 LDS tiles
// (async-STAGE split: loads for kt+1 issued before compute of kt).
// M=8192, N=768, K=256; 128x128 tile, BK=32, 4 waves.
// ---------------------------------------------------------------------------
__global__ __launch_bounds__(256) void gemm_qkv(
    const float* __restrict__ A, const float* __restrict__ W,
    const float* __restrict__ bias, __hip_bfloat16* __restrict__ Cb,
    const int* __restrict__ lens) {
  __shared__ __bf16 As[2][128][32];
  __shared__ __bf16 Bs[2][128][32];

  const int tid = threadIdx.x;
  const int w = tid >> 6;
  const int lane = tid & 63;
  const int c = lane & 15;
  const int hq = lane >> 4;
  const int h8 = hq << 3;
  const int wr = w >> 1, wc = w & 1;
  const int c0 = blockIdx.x << 7;
  const int r0 = blockIdx.y << 7;
  if ((r0 & (LL - 1)) >= lens[r0 >> 10]) return;  // dead tile

  const int srow = tid >> 2;       // 0..63
  const int scol = (tid & 3) << 3; // 0,8,16,24

  float4 ra[2][2], rb[2][2];
  auto LOADR = [&](int kt) {
    const int k0 = kt << 5;
#pragma unroll
    for (int ch = 0; ch < 2; ++ch) {
      const float* ap = A + (size_t)(r0 + (ch << 6) + srow) * DD + k0 + scol;
      ra[ch][0] = *(const float4*)ap;
      ra[ch][1] = *(const float4*)(ap + 4);
      const float* wp = W + (size_t)(c0 + (ch << 6) + srow) * DD + k0 + scol;
      rb[ch][0] = *(const float4*)wp;
      rb[ch][1] = *(const float4*)(wp + 4);
    }
  };
  auto WRITEL = [&](int buf) {
#pragma unroll
    for (int ch = 0; ch < 2; ++ch) {
      *(bf16x8*)&As[buf][(ch << 6) + srow][scol] = cvt8(ra[ch][0], ra[ch][1]);
      *(bf16x8*)&Bs[buf][(ch << 6) + srow][scol] = cvt8(rb[ch][0], rb[ch][1]);
    }
  };

  f32x4 acc[4][4];
#pragma unroll
  for (int m = 0; m < 4; ++m)
#pragma unroll
    for (int n = 0; n < 4; ++n) acc[m][n] = (f32x4){0.f, 0.f, 0.f, 0.f};

  int buf = 0;
  LOADR(0);
  WRITEL(0);
  __syncthreads();
  for (int kt = 0; kt < 8; ++kt) {
    if (kt + 1 < 8) LOADR(kt + 1);
    bf16x8 af[4], bfr[4];
#pragma unroll
    for (int m = 0; m < 4; ++m)
      af[m] = *(const bf16x8*)&As[buf][wr * 64 + (m << 4) + c][h8];
#pragma unroll
    for (int n = 0; n < 4; ++n)
      bfr[n] = *(const bf16x8*)&Bs[buf][(wc << 6) + (n << 4) + c][h8];
#pragma unroll
    for (int m = 0; m < 4; ++m)
#pragma unroll
      for (int n = 0; n < 4; ++n)
        acc[m][n] =
            __builtin_amdgcn_mfma_f32_16x16x32_bf16(af[m], bfr[n], acc[m][n], 0, 0, 0);
    if (kt + 1 < 8) WRITEL(buf ^ 1);
    __syncthreads();
    buf ^= 1;
  }

  float bv[4];
#pragma unroll
  for (int n = 0; n < 4; ++n) bv[n] = bias[c0 + (wc << 6) + (n << 4) + c];
#pragma unroll
  for (int m = 0; m < 4; ++m)
#pragma unroll
    for (int i = 0; i < 4; ++i) {
      const int gr = r0 + wr * 64 + (m << 4) + (hq << 2) + i;
#pragma unroll
      for (int n = 0; n < 4; ++n)
        Cb[(size_t)gr * 768 + c0 + (wc << 6) + (n << 4) + c] =
            (__hip_bfloat16)(acc[m][n][i] + bv[n]);
    }
}

// ---------------------------------------------------------------------------
// bf16 MFMA NT GEMM (m97 structure): C = A[M,K]_bf16 @ W[N,K]_bf16^T + epi.
// EPI: 1 = +bias,gelu -> bf16; 2 = +bias+resid(f32) -> f32 AND bf16
// ---------------------------------------------------------------------------
template <int EPI, int BM>
__global__ __launch_bounds__(256) void gemm_bf16(
    const __hip_bfloat16* __restrict__ A, const __hip_bfloat16* __restrict__ W,
    const float* __restrict__ bias, const float* __restrict__ resid,
    float* __restrict__ Cf, __hip_bfloat16* __restrict__ Cb, const int M,
    const int N, const int K, const int* __restrict__ lens) {
  constexpr int MF = BM / 32;
  constexpr int CH = BM / 64;
  __shared__ __bf16 As[2][BM][32];
  __shared__ __bf16 Bs[2][128][32];

  const int tid = threadIdx.x;
  const int w = tid >> 6;
  const int lane = tid & 63;
  const int c = lane & 15;
  const int hq = lane >> 4;
  const int h8 = hq << 3;
  const int wr = w >> 1, wc = w & 1;
  const int c0 = blockIdx.x << 7;
  const int r0 = blockIdx.y * BM;
  if ((r0 & (LL - 1)) >= lens[r0 >> 10]) return;  // dead tile

  const int srow = tid >> 2;
  const int scol = (tid & 3) << 3;

  auto STAGE = [&](int buf, int kt) {
    const int k0 = kt << 5;
#pragma unroll
    for (int ch = 0; ch < CH; ++ch)
      gload16(A + (size_t)(r0 + (ch << 6) + srow) * K + k0 + scol,
              &As[buf][(ch << 6) + (w << 4)][0]);
#pragma unroll
    for (int ch = 0; ch < 2; ++ch)
      gload16(W + (size_t)(c0 + (ch << 6) + srow) * K + k0 + scol,
              &Bs[buf][(ch << 6) + (w << 4)][0]);
  };

  f32x4 acc[MF][4];
#pragma unroll
  for (int m = 0; m < MF; ++m)
#pragma unroll
    for (int n = 0; n < 4; ++n) acc[m][n] = (f32x4){0.f, 0.f, 0.f, 0.f};

  const int nkt = K >> 5;
  int buf = 0;
  STAGE(0, 0);
  __syncthreads();
  for (int kt = 0; kt < nkt; ++kt) {
    if (kt + 1 < nkt) STAGE(buf ^ 1, kt + 1);
    bf16x8 af[MF], bfr[4];
#pragma unroll
    for (int m = 0; m < MF; ++m)
      af[m] = *(const bf16x8*)&As[buf][wr * (MF * 16) + (m << 4) + c][h8];
#pragma unroll
    for (int n = 0; n < 4; ++n)
      bfr[n] = *(const bf16x8*)&Bs[buf][(wc << 6) + (n << 4) + c][h8];
#pragma unroll
    for (int m = 0; m < MF; ++m)
#pragma unroll
      for (int n = 0; n < 4; ++n)
        acc[m][n] =
            __builtin_amdgcn_mfma_f32_16x16x32_bf16(af[m], bfr[n], acc[m][n], 0, 0, 0);
    __syncthreads();
    buf ^= 1;
  }

  float bv[4];
#pragma unroll
  for (int n = 0; n < 4; ++n) bv[n] = bias[c0 + (wc << 6) + (n << 4) + c];

#pragma unroll
  for (int m = 0; m < MF; ++m) {
#pragma unroll
    for (int i = 0; i < 4; ++i) {
      const int gr = r0 + wr * (MF * 16) + (m << 4) + (hq << 2) + i;
#pragma unroll
      for (int n = 0; n < 4; ++n) {
        const int gc = c0 + (wc << 6) + (n << 4) + c;
        float v = acc[m][n][i] + bv[n];
        if (EPI == 1) v = 0.5f * v * (1.0f + erff(v * 0.70710678118654752f));
        if (EPI == 2) {
          v += resid[(size_t)gr * N + gc];
          Cf[(size_t)gr * N + gc] = v;
        }
        Cb[(size_t)gr * N + gc] = (__hip_bfloat16)v;
      }
    }
  }
}

// ---------------------------------------------------------------------------
// FF2 split-K partial: P[z][M][256](bf16) = A[M, z*512:(z+1)*512] @ W^T slice.
// ---------------------------------------------------------------------------
__global__ __launch_bounds__(256) void gemm_ff2_part(
    const __hip_bfloat16* __restrict__ A, const __hip_bfloat16* __restrict__ W,
    __hip_bfloat16* __restrict__ P, const int* __restrict__ lens) {
  constexpr int MF = 2;
  __shared__ __bf16 As[2][64][32];
  __shared__ __bf16 Bs[2][128][32];

  const int tid = threadIdx.x;
  const int w = tid >> 6;
  const int lane = tid & 63;
  const int c = lane & 15;
  const int hq = lane >> 4;
  const int h8 = hq << 3;
  const int wr = w >> 1, wc = w & 1;
  const int c0 = blockIdx.x << 7;
  const int r0 = blockIdx.y << 6;
  if ((r0 & (LL - 1)) >= lens[r0 >> 10]) return;

  const int kz = blockIdx.z;
  const int kbase = kz << 9;
  const int srow = tid >> 2;
  const int scol = (tid & 3) << 3;

  auto STAGE = [&](int buf, int kt) {
    const int k0 = kbase + (kt << 5);
    gload16(A + (size_t)(r0 + srow) * DFFN + k0 + scol, &As[buf][w << 4][0]);
#pragma unroll
    for (int ch = 0; ch < 2; ++ch)
      gload16(W + (size_t)(c0 + (ch << 6) + srow) * DFFN + k0 + scol,
              &Bs[buf][(ch << 6) + (w << 4)][0]);
  };

  f32x4 acc[MF][4];
#pragma unroll
  for (int m = 0; m < MF; ++m)
#pragma unroll
    for (int n = 0; n < 4; ++n) acc[m][n] = (f32x4){0.f, 0.f, 0.f, 0.f};

  int buf = 0;
  STAGE(0, 0);
  __syncthreads();
  for (int kt = 0; kt < 16; ++kt) {
    if (kt + 1 < 16) STAGE(buf ^ 1, kt + 1);
    bf16x8 af[MF], bfr[4];
#pragma unroll
    for (int m = 0; m < MF; ++m)
      af[m] = *(const bf16x8*)&As[buf][wr * (MF * 16) + (m << 4) + c][h8];
#pragma unroll
    for (int n = 0; n < 4; ++n)
      bfr[n] = *(const bf16x8*)&Bs[buf][(wc << 6) + (n << 4) + c][h8];
#pragma unroll
    for (int m = 0; m < MF; ++m)
#pragma unroll
      for (int n = 0; n < 4; ++n)
        acc[m][n] =
            __builtin_amdgcn_mfma_f32_16x16x32_bf16(af[m], bfr[n], acc[m][n], 0, 0, 0);
    __syncthreads();
    buf ^= 1;
  }

  __hip_bfloat16* Pz = P + (size_t)kz * (BB * LL) * DD;
#pragma unroll
  for (int m = 0; m < MF; ++m)
#pragma unroll
    for (int i = 0; i < 4; ++i) {
      const int gr = r0 + wr * (MF * 16) + (m << 4) + (hq << 2) + i;
#pragma unroll
      for (int n = 0; n < 4; ++n)
        Pz[(size_t)gr * DD + c0 + (wc << 6) + (n << 4) + c] =
            (__hip_bfloat16)acc[m][n][i];
    }
}

// ---------------------------------------------------------------------------
// FF2 reduce: out = resid + bias + sum_z P[z] (bf16 partials), zero pad rows.
// ---------------------------------------------------------------------------
__global__ __launch_bounds__(256) void ff2_reduce(
    const __hip_bfloat16* __restrict__ P, const float* __restrict__ resid,
    const float* __restrict__ bias, float* __restrict__ out,
    const int* __restrict__ lens) {
  const int idx = blockIdx.x * 256 + threadIdx.x;  // one float4
  const int r = idx >> 6;
  const int c4 = (idx & 63) << 2;
  float4 o;
  if ((r & (LL - 1)) >= lens[r >> 10]) {
    o.x = o.y = o.z = o.w = 0.f;
  } else {
    const size_t base = (size_t)r * DD + c4;
    o = *(const float4*)&resid[base];
    const float4 bv = *(const float4*)&bias[c4];
    o.x += bv.x; o.y += bv.y; o.z += bv.z; o.w += bv.w;
#pragma unroll
    for (int z = 0; z < 4; ++z) {
      const __hip_bfloat16* pz = P + (size_t)z * (BB * LL) * DD + base;
      ushort4 pu = *(const ushort4*)pz;
      o.x += __bfloat162float(*(const __hip_bfloat16*)&pu.x);
      o.y += __bfloat162float(*(const __hip_bfloat16*)&pu.y);
      o.z += __bfloat162float(*(const __hip_bfloat16*)&pu.z);
      o.w += __bfloat162float(*(const __hip_bfloat16*)&pu.w);
    }
  }
  *(float4*)&out[(size_t)r * DD + c4] = o;
}

// ---------------------------------------------------------------------------
// MFMA bf16 flash attention, static-max softmax (shift-invariant, m=8),
// LDS dbuf K/V (one barrier/tile), full-tile fast path, setprio on MFMA.
// ---------------------------------------------------------------------------
__global__ __launch_bounds__(256) void attn_fwd_mfma(
    const __hip_bfloat16* __restrict__ qkv, __hip_bfloat16* __restrict__ ctx,
    const int* __restrict__ lens) {
  __shared__ __bf16 Ks[2][64][56];
  __shared__ __bf16 Vt[2][32][66];
  __shared__ __bf16 Pl[4][16][72];

  const int tid = threadIdx.x;
  const int q0 = blockIdx.x << 6;
  const int hh = blockIdx.y;
  const int b = blockIdx.z;
  const int slen = lens[b];
  if (q0 >= slen) return;  // padded q rows are zeroed downstream

  const int w = tid >> 6;
  const int lane = tid & 63;
  const int c = lane & 15;
  const int h = lane >> 4;
  const int h8 = h << 3;

  const float L2E = 1.44269504f;
  const float sf = (float)slen;
  const float cb = -7.0f * L2E;
  const float cd = (1.0f / sf) * L2E;
  const float qscale = 0.17677669529663689f * L2E;

  bf16x8 qf;
  {
    const int qrow = q0 + (w << 4) + c;
    const bf16x8 qraw =
        *(const bf16x8*)(qkv + (size_t)(b * LL + qrow) * 768 + hh * DHH + h8);
#pragma unroll
    for (int j = 0; j < 8; ++j) qf[j] = (__bf16)((float)qraw[j] * qscale);
  }

  f32x4 acc0 = {0.f, 0.f, 0.f, 0.f};
  f32x4 acc1 = {0.f, 0.f, 0.f, 0.f};
  float lsum[4] = {0.f, 0.f, 0.f, 0.f};

  const int skey = tid >> 2;
  const int sdg = (tid & 3) << 3;
  const int ntk = (slen + 63) >> 6;
  const int qg = q0 + (w << 4) + (h << 2);

  const __hip_bfloat16* kvbase = qkv + (size_t)b * LL * 768 + 256 + hh * DHH + sdg;

  bf16x8 kreg, vreg;
  {
    const __hip_bfloat16* kb = kvbase + (size_t)skey * 768;
    kreg = *(const bf16x8*)kb;
    vreg = *(const bf16x8*)(kb + 256);
    *(bf16x8*)&Ks[0][skey][sdg] = kreg;
#pragma unroll
    for (int j = 0; j < 8; ++j) Vt[0][sdg + j][skey] = vreg[j];
  }
  if (ntk > 1) {
    const __hip_bfloat16* kb = kvbase + (size_t)(64 + skey) * 768;
    kreg = *(const bf16x8*)kb;
    vreg = *(const bf16x8*)(kb + 256);
  }
  __syncthreads();

  for (int kt = 0; kt < ntk; ++kt) {
    const int p = kt & 1;
    const int kbase = kt << 6;

    f32x4 st[4];
    __builtin_amdgcn_s_setprio(1);
#pragma unroll
    for (int t = 0; t < 4; ++t) {
      const bf16x8 kf = *(const bf16x8*)&Ks[p][(t << 4) + c][h8];
      st[t] = __builtin_amdgcn_mfma_f32_16x16x32_bf16(
          qf, kf, (f32x4){0.f, 0.f, 0.f, 0.f}, 0, 0, 0);
    }
    __builtin_amdgcn_s_setprio(0);

    if (kbase + 64 <= slen) {
      // full tile: no key-validity check
#pragma unroll
      for (int t = 0; t < 4; ++t) {
        const float kjf = (float)(kbase + (t << 4) + c);
#pragma unroll
        for (int i = 0; i < 4; ++i) {
          const float dist = fabsf((float)(qg + i) - kjf);
          const float pv = __builtin_amdgcn_exp2f(st[t][i] + cb - dist * cd);
          lsum[i] += pv;
          Pl[w][(h << 2) + i][c + (t << 4)] = (__bf16)pv;
        }
      }
    } else {
#pragma unroll
      for (int t = 0; t < 4; ++t) {
        const int kj = kbase + (t << 4) + c;
        const bool kvalid = kj < slen;
        const float kjf = (float)kj;
#pragma unroll
        for (int i = 0; i < 4; ++i) {
          const float dist = fabsf((float)(qg + i) - kjf);
          const float arg = kvalid ? (st[t][i] + cb - dist * cd) : -1e30f;
          const float pv = __builtin_amdgcn_exp2f(arg);
          lsum[i] += pv;
          Pl[w][(h << 2) + i][c + (t << 4)] = (__bf16)pv;
        }
      }
    }

    asm volatile("s_waitcnt lgkmcnt(0)" ::: "memory");

    __builtin_amdgcn_s_setprio(1);
#pragma unroll
    for (int n = 0; n < 2; ++n) {
      const bf16x8 pf = *(const bf16x8*)&Pl[w][c][h8 + (n << 5)];
      const uint32_t* v0p = (const uint32_t*)&Vt[p][c][h8 + (n << 5)];
      const uint32_t* v1p = (const uint32_t*)&Vt[p][16 + c][h8 + (n << 5)];
      union { uint32_t u[4]; bf16x8 v; } t0, t1;
#pragma unroll
      for (int j = 0; j < 4; ++j) { t0.u[j] = v0p[j]; t1.u[j] = v1p[j]; }
      acc0 = __builtin_amdgcn_mfma_f32_16x16x32_bf16(pf, t0.v, acc0, 0, 0, 0);
      acc1 = __builtin_amdgcn_mfma_f32_16x16x32_bf16(pf, t1.v, acc1, 0, 0, 0);
    }
    __builtin_amdgcn_s_setprio(0);

    if (kt + 1 < ntk) {
      *(bf16x8*)&Ks[p ^ 1][skey][sdg] = kreg;
#pragma unroll
      for (int j = 0; j < 8; ++j) Vt[p ^ 1][sdg + j][skey] = vreg[j];
      if (kt + 2 < ntk) {
        const __hip_bfloat16* kb = kvbase + (size_t)(((kt + 2) << 6) + skey) * 768;
        kreg = *(const bf16x8*)kb;
        vreg = *(const bf16x8*)(kb + 256);
      }
    }
    __syncthreads();
  }

#pragma unroll
  for (int i = 0; i < 4; ++i) {
    float l = lsum[i];
    l += __shfl_xor(l, 1);
    l += __shfl_xor(l, 2);
    l += __shfl_xor(l, 4);
    l += __shfl_xor(l, 8);
    const float il = 1.0f / l;
    __hip_bfloat16* op =
        ctx + (size_t)(b * LL + q0 + (w << 4) + (h << 2) + i) * 256 + hh * DHH;
    op[c] = (__hip_bfloat16)(acc0[i] * il);
    op[c + 16] = (__hip_bfloat16)(acc1[i] * il);
  }
}

// ---------------------------------------------------------------------------
extern "C" void kernel_launch(void* const* d_in, const int* in_sizes, int n_in,
                              void* d_out, int out_size, void* d_ws,
                              size_t ws_size, hipStream_t stream) {
  (void)in_sizes; (void)n_in; (void)out_size; (void)ws_size;
  const float* src = (const float*)d_in[0];
  const unsigned char* mask = (const unsigned char*)d_in[1];
  const float* in_proj_w = (const float*)d_in[2];
  const float* in_proj_b = (const float*)d_in[3];
  const float* out_w = (const float*)d_in[4];
  const float* out_b = (const float*)d_in[5];
  const float* proj_w = (const float*)d_in[6];
  const float* proj_b = (const float*)d_in[7];
  const float* ff1_w = (const float*)d_in[8];
  const float* ff1_b = (const float*)d_in[9];
  const float* ff2_w = (const float*)d_in[10];
  const float* ff2_b = (const float*)d_in[11];
  float* out = (float*)d_out;

  const int M = BB * LL;  // 8192
  char* p = (char*)d_ws;
  __hip_bfloat16* qkv_bf = (__hip_bfloat16*)p; p += (size_t)M * 768 * 2;
  __hip_bfloat16* ctx_bf = (__hip_bfloat16*)p; p += (size_t)M * 256 * 2;
  float* hbuf_f = (float*)p;                    p += (size_t)M * 256 * 4;
  __hip_bfloat16* hbuf_bf = (__hip_bfloat16*)p; p += (size_t)M * 256 * 2;
  __hip_bfloat16* ff1o_bf = (__hip_bfloat16*)p; p += (size_t)M * 2048 * 2;
  __hip_bfloat16* wff1_bf = (__hip_bfloat16*)p; p += (size_t)2048 * 256 * 2;
  __hip_bfloat16* wff2_bf = (__hip_bfloat16*)p; p += (size_t)256 * 2048 * 2;
  __hip_bfloat16* wc_bf = (__hip_bfloat16*)p;   p += (size_t)256 * 256 * 2;
  float* bc = (float*)p;                        p += 256 * 4;
  int* lens = (int*)p;                          p += 256;
  __hip_bfloat16* pbuf = (__hip_bfloat16*)p;    p += (size_t)4 * M * 256 * 2;

  // preamble: lens + weight cvt (ff1/ff2) + fused proj@out weight
  preamble_kernel<<<NB_CVT + 1 + 64, 256, 0, stream>>>(
      mask, ff1_w, ff2_w, proj_w, out_w, proj_b, out_b, wff1_bf, wff2_bf,
      wc_bf, bc, lens);

  // qkv = src @ in_proj^T + b   [8192 x 768], fp32 in (fused cvt), bf16 out
  gemm_qkv<<<dim3(6, 64), 256, 0, stream>>>(src, in_proj_w, in_proj_b, qkv_bf,
                                            lens);
  // attention
  attn_fwd_mfma<<<dim3(LL / 64, HHN, BB), 256, 0, stream>>>(qkv_bf, ctx_bf, lens);
  // hbuf = src + ctx @ Wc^T + bc   [8192 x 256], f32 + bf16 out
  gemm_bf16<2, 64><<<dim3(2, 128), 256, 0, stream>>>(
      ctx_bf, wc_bf, bc, src, hbuf_f, hbuf_bf, M, 256, 256, lens);
  // ff1o = gelu(hbuf @ ff1^T + b)  [8192 x 2048], bf16 out
  gemm_bf16<1, 128><<<dim3(16, 64), 256, 0, stream>>>(
      hbuf_bf, wff1_bf, ff1_b, nullptr, nullptr, ff1o_bf, M, 2048, 256, lens);
  // FF2 split-K x4 bf16 partials, then reduce (+resid +bias, zero pad rows)
  gemm_ff2_part<<<dim3(2, 128, 4), 256, 0, stream>>>(ff1o_bf, wff2_bf, pbuf, lens);
  ff2_reduce<<<M * 256 / 4 / 256, 256, 0, stream>>>(pbuf, hbuf_f, ff2_b, out, lens);
}